// Round 15
// baseline (189.287 us; speedup 1.0000x reference)
//
#include <hip/hip_runtime.h>
#include <hip/hip_bf16.h>

#define BSz 2
#define Nn 15135
#define Ee 242160
#define F_INc 8
#define Hh 64
#define Ll 4
#define HFCc 256
#define NCc 10
#define EPSg 1e-15f
#define NBLK ((Nn + 255) / 256)   // 60 scan blocks
#define MROWS (2 * Nn)            // 30270 A-rows (row = 2n + b)
#define MTILES ((MROWS + 15) / 16)

typedef __attribute__((ext_vector_type(8))) short short8;
typedef __attribute__((ext_vector_type(4))) float f32x4;

__device__ __forceinline__ float uf(unsigned u) { return __uint_as_float(u); }
__device__ __forceinline__ unsigned short bs16(float f) {
    unsigned b = __float_as_uint(f);
    return (unsigned short)((b + 0x7FFFu + ((b >> 16) & 1u)) >> 16);
}
__device__ __forceinline__ unsigned packbf(float a, float b) {
    return (unsigned)bs16(a) | ((unsigned)bs16(b) << 16);
}

// ---- init ----------------------------------------------------------------

__global__ void zero_kernel(int* __restrict__ cursor, float* __restrict__ h1acc) {
    int i = blockIdx.x * 256 + threadIdx.x;
    if (i < Nn) cursor[i] = 0;
    if (i < BSz * HFCc) h1acc[i] = 0.f;
}

// x (2,N,8) f32 -> xi[n*8+f] = packed bf16 {b0,b1}
__global__ void pack_x(const float* __restrict__ x, unsigned* __restrict__ xi) {
    int i = blockIdx.x * 256 + threadIdx.x;
    if (i < Nn * F_INc) xi[i] = packbf(x[i], x[(size_t)Nn * F_INc + i]);
}

// weights: wbuf u32[768] for layer0 (as R13); wbt ushort[3][64][200] = B^T
__global__ void pack_weights(const float* __restrict__ g1, const float* __restrict__ root1,
                             const float* __restrict__ gs, const float* __restrict__ roots,
                             unsigned* __restrict__ wbuf, unsigned short* __restrict__ wbt) {
    int i = blockIdx.x * 256 + threadIdx.x;
    if (i < 512) {
        int f = i >> 6, h = i & 63;
        wbuf[i] = packbf(g1[f * 128 + h], g1[f * 128 + 64 + h]);
    } else if (i < 768) {
        int j = i - 512; int f2 = j >> 6, h = j & 63;
        wbuf[i] = packbf(root1[(2 * f2) * 64 + h], root1[(2 * f2 + 1) * 64 + h]);
    }
    if (i < 3 * 64 * 200) {
        int l = i / 12800, r = i % 12800, c = r / 200, k = r % 200;
        const float* G = gs + (size_t)l * 64 * 128;
        const float* R = roots + (size_t)l * 64 * 64;
        float v = 0.f;
        if (k < 64)       v = G[k * 128 + c];
        else if (k < 128) v = G[(k - 64) * 128 + 64 + c];
        else if (k < 192) v = R[(k - 128) * 64 + c];
        wbt[i] = bs16(v);
    }
}

// ---- CSR build ----------------------------------------------------------

__global__ void count_kernel(const int* __restrict__ dst, int* __restrict__ cnt) {
    int e = blockIdx.x * blockDim.x + threadIdx.x;
    if (e < Ee) atomicAdd(&cnt[dst[e]], 1);
}

__global__ void scan_local(const int* __restrict__ cnt, int* __restrict__ loc,
                           int* __restrict__ bsum) {
    int tid = threadIdx.x, lane = tid & 63, w = tid >> 6;
    int i = blockIdx.x * 256 + tid;
    __shared__ int ws[4];
    int v = (i < Nn) ? cnt[i] : 0;
    int incl = v;
#pragma unroll
    for (int d = 1; d < 64; d <<= 1) {
        int t = __shfl_up(incl, d, 64);
        if (lane >= d) incl += t;
    }
    if (lane == 63) ws[w] = incl;
    __syncthreads();
    int pre = 0;
    for (int ww = 0; ww < w; ++ww) pre += ws[ww];
    if (i < Nn) loc[i] = pre + incl - v;
    if (tid == 255) bsum[blockIdx.x] = pre + incl;
}

__global__ void scan_tops(int* __restrict__ bsum) {
    int lane = threadIdx.x;
    int v = (lane < NBLK) ? bsum[lane] : 0;
    int incl = v;
#pragma unroll
    for (int d = 1; d < 64; d <<= 1) {
        int t = __shfl_up(incl, d, 64);
        if (lane >= d) incl += t;
    }
    if (lane < NBLK) bsum[lane] = incl - v;
}

__global__ void scan_fix(const int* __restrict__ loc, const int* __restrict__ bsum,
                         int* __restrict__ offs, int* __restrict__ cursor) {
    int i = blockIdx.x * 256 + threadIdx.x;
    if (i < Nn) {
        int o = loc[i] + bsum[blockIdx.x];
        offs[i] = o;
        cursor[i] = o;
    }
    if (i == 0) offs[Nn] = Ee;
}

// fill CSR + per-layer gauss arrays gauss[l*E + p]
__global__ void fill_kernel(const int* __restrict__ src, const int* __restrict__ dst,
                            const float* __restrict__ pseudo, int* __restrict__ cursor,
                            int* __restrict__ csr_src, float2* __restrict__ gauss,
                            const float* __restrict__ mu1, const float* __restrict__ sigma1,
                            const float* __restrict__ mus, const float* __restrict__ sigmas) {
    int e = blockIdx.x * blockDim.x + threadIdx.x;
    if (e >= Ee) return;
    int p = atomicAdd(&cursor[dst[e]], 1);
    csr_src[p] = src[e];
    float2 ps = ((const float2*)pseudo)[e];
#pragma unroll
    for (int l = 0; l < Ll; ++l) {
        const float* mu = (l == 0) ? mu1 : mus + (l - 1) * 4;
        const float* sg = (l == 0) ? sigma1 : sigmas + (l - 1) * 4;
        float d00 = ps.x - mu[0], d01 = ps.y - mu[1];
        float d10 = ps.x - mu[2], d11 = ps.y - mu[3];
        float i00 = 1.f / (EPSg + sg[0] * sg[0]);
        float i01 = 1.f / (EPSg + sg[1] * sg[1]);
        float i10 = 1.f / (EPSg + sg[2] * sg[2]);
        float i11 = 1.f / (EPSg + sg[3] * sg[3]);
        float g0 = expf(-0.5f * (d00 * d00 * i00 + d01 * d01 * i01));
        float g1 = expf(-0.5f * (d10 * d10 * i10 + d11 * d11 * i11));
        gauss[(size_t)l * Ee + p] = make_float2(g0, g1);
    }
}

// ---- layer 0 fused (unchanged from R13) ----------------------------------
__global__ __launch_bounds__(512, 4)
void layer0_fused(const unsigned* __restrict__ xi, const int* __restrict__ offs,
                  const int* __restrict__ csr_src, const float2* __restrict__ gauss,
                  const unsigned* __restrict__ wG, const unsigned* __restrict__ wR,
                  const float* __restrict__ bias, const float* __restrict__ fc_w,
                  unsigned* __restrict__ hpout, float* __restrict__ node) {
    int tid = threadIdx.x;
    int lane = tid & 63;
    int r = tid >> 6;
    int n0 = blockIdx.x * 8;
    int n = n0 + r;
    __shared__ unsigned sG[F_INc * 64];
    __shared__ unsigned sR[4 * 64];
    __shared__ unsigned s_agg[8][2 * F_INc];
    __shared__ unsigned s_x[8][F_INc];
    if (tid < F_INc * 64) sG[tid] = wG[tid];
    if (tid < 256) sR[tid] = wR[tid];
    for (int idx = tid; idx < 8 * F_INc; idx += 512) {
        int rr = idx >> 3, ff = idx & 7;
        int gn = n0 + rr;
        s_x[rr][ff] = (gn < Nn) ? xi[(size_t)gn * F_INc + ff] : 0u;
    }
    if (n < Nn) {
        int esub = lane >> 3, f = lane & 7;
        int s0 = offs[n], s1 = offs[n + 1];
        float a00 = 0.f, a01 = 0.f, a10 = 0.f, a11 = 0.f;
        if (s1 > s0) {
            int last = s1 - 1;
            for (int p0 = s0; p0 <= last; p0 += 8) {
                int p = p0 + esub;
                int pc = p < last ? p : last;
                float2 g = gauss[pc];
                if (p > last) { g.x = 0.f; g.y = 0.f; }
                unsigned u = xi[csr_src[pc] * F_INc + f];
                float x0 = uf(u << 16), x1 = uf(u & 0xFFFF0000u);
                a00 += g.x * x0; a01 += g.x * x1;
                a10 += g.y * x0; a11 += g.y * x1;
            }
#pragma unroll
            for (int d = 8; d <= 32; d <<= 1) {
                a00 += __shfl_xor(a00, d, 64);
                a01 += __shfl_xor(a01, d, 64);
                a10 += __shfl_xor(a10, d, 64);
                a11 += __shfl_xor(a11, d, 64);
            }
        }
        if (lane < 8) {
            s_agg[r][f]         = packbf(a00, a01);
            s_agg[r][F_INc + f] = packbf(a10, a11);
        }
    }
    __syncthreads();
    if (n >= Nn) return;
    int h = lane;
    float dg = (float)(offs[n + 1] - offs[n]);
    if (dg < 1.f) dg = 1.f;
    float inv = 1.f / dg;
    float bv = bias[h];
    float aA0 = 0.f, aA1 = 0.f, aR0 = bv, aR1 = bv;
#pragma unroll
    for (int f = 0; f < F_INc; ++f) {
        unsigned g = sG[f * 64 + h];
        float gv0 = uf(g << 16), gv1 = uf(g & 0xFFFF0000u);
        unsigned u0 = s_agg[r][f], u1 = s_agg[r][F_INc + f];
        aA0 = fmaf(uf(u0 << 16), gv0, aA0);
        aA1 = fmaf(uf(u0 & 0xFFFF0000u), gv0, aA1);
        aA0 = fmaf(uf(u1 << 16), gv1, aA0);
        aA1 = fmaf(uf(u1 & 0xFFFF0000u), gv1, aA1);
    }
#pragma unroll
    for (int f2 = 0; f2 < 4; ++f2) {
        unsigned rp = sR[f2 * 64 + h];
        float rv0 = uf(rp << 16), rv1 = uf(rp & 0xFFFF0000u);
        unsigned p0 = s_x[r][2 * f2], p1 = s_x[r][2 * f2 + 1];
        aR0 = fmaf(uf(p0 << 16), rv0, aR0);
        aR1 = fmaf(uf(p0 & 0xFFFF0000u), rv0, aR1);
        aR0 = fmaf(uf(p1 << 16), rv1, aR0);
        aR1 = fmaf(uf(p1 & 0xFFFF0000u), rv1, aR1);
    }
    float val0 = fmaf(aA0, inv, aR0);
    float val1 = fmaf(aA1, inv, aR1);
    val0 = val0 > 0.f ? val0 : expm1f(val0);
    val1 = val1 > 0.f ? val1 : expm1f(val1);
    hpout[(size_t)n * 64 + h] = packbf(val0, val1);
    float fw = fc_w[h * Ll + 0];
    float r0 = val0 * fw, r1 = val1 * fw;
#pragma unroll
    for (int off = 32; off; off >>= 1) {
        r0 += __shfl_down(r0, off, 64);
        r1 += __shfl_down(r1, off, 64);
    }
    if (h == 0) { node[n] = r0; node[Nn + n] = r1; }
}

// ---- layers 1..3: gather -> A rows; TWO waves per node (edge halves) -----
__global__ __launch_bounds__(512, 4)
void gatherA(const unsigned* __restrict__ hp, const int* __restrict__ offs,
             const int* __restrict__ csr_src, const float2* __restrict__ gauss,
             unsigned short* __restrict__ A) {
    int tid = threadIdx.x;
    int lane = tid & 63;
    int wid = tid >> 6;        // 0..7
    int r = wid >> 1;          // node slot 0..3
    int sub = wid & 1;         // edge-half
    int n = blockIdx.x * 4 + r;
    __shared__ float4 part[4][2][64];   // 8 KB
    float a00 = 0.f, a01 = 0.f, a10 = 0.f, a11 = 0.f;  // a[k][b]
    int s0 = 0, s1 = 0;
    if (n < Nn) {
        s0 = offs[n]; s1 = offs[n + 1];
        int half = (s1 - s0 + 1) >> 1;
        int b0 = s0 + sub * half;
        int b1 = b0 + half < s1 ? b0 + half : s1;
        int p = b0;
        for (; p + 3 < b1; p += 4) {
            int sa = csr_src[p], sb = csr_src[p + 1], sc = csr_src[p + 2], sd = csr_src[p + 3];
            float2 ga = gauss[p], gb = gauss[p + 1], gc = gauss[p + 2], gd = gauss[p + 3];
            unsigned ua = hp[(size_t)sa * 64 + lane];
            unsigned ub = hp[(size_t)sb * 64 + lane];
            unsigned uc = hp[(size_t)sc * 64 + lane];
            unsigned ud = hp[(size_t)sd * 64 + lane];
            float xa0 = uf(ua << 16), xa1 = uf(ua & 0xFFFF0000u);
            float xb0 = uf(ub << 16), xb1 = uf(ub & 0xFFFF0000u);
            float xc0 = uf(uc << 16), xc1 = uf(uc & 0xFFFF0000u);
            float xd0 = uf(ud << 16), xd1 = uf(ud & 0xFFFF0000u);
            a00 += ga.x * xa0 + gb.x * xb0 + gc.x * xc0 + gd.x * xd0;
            a01 += ga.x * xa1 + gb.x * xb1 + gc.x * xc1 + gd.x * xd1;
            a10 += ga.y * xa0 + gb.y * xb0 + gc.y * xc0 + gd.y * xd0;
            a11 += ga.y * xa1 + gb.y * xb1 + gc.y * xc1 + gd.y * xd1;
        }
        for (; p < b1; ++p) {
            int sa = csr_src[p];
            float2 ga = gauss[p];
            unsigned ua = hp[(size_t)sa * 64 + lane];
            float xa0 = uf(ua << 16), xa1 = uf(ua & 0xFFFF0000u);
            a00 += ga.x * xa0; a01 += ga.x * xa1;
            a10 += ga.y * xa0; a11 += ga.y * xa1;
        }
    }
    part[r][sub][lane] = make_float4(a00, a01, a10, a11);
    __syncthreads();
    if (n >= Nn || sub) return;
    float4 o = part[r][1][lane];
    a00 += o.x; a01 += o.y; a10 += o.z; a11 += o.w;
    float dg = (float)(s1 - s0);
    if (dg < 1.f) dg = 1.f;
    float inv = 1.f / dg;
    unsigned short* r0 = A + (size_t)(2 * n) * 192;
    unsigned short* r1 = A + (size_t)(2 * n + 1) * 192;
    r0[lane]       = bs16(a00 * inv);
    r0[64 + lane]  = bs16(a10 * inv);
    r1[lane]       = bs16(a01 * inv);
    r1[64 + lane]  = bs16(a11 * inv);
    unsigned up = hp[(size_t)n * 64 + lane];
    r0[128 + lane] = (unsigned short)(up & 0xFFFFu);
    r1[128 + lane] = (unsigned short)(up >> 16);
}

// ---- MFMA combine (unchanged from R14) -----------------------------------
__global__ __launch_bounds__(256, 4)
void mfma_combine(const unsigned short* __restrict__ A, const unsigned short* __restrict__ wbt,
                  const float* __restrict__ bias, const float* __restrict__ fc_w, int l,
                  unsigned* __restrict__ hpout, float* __restrict__ node) {
    __shared__ unsigned short sB[64 * 200];
    int tid = threadIdx.x;
    {
        const uint4* s = (const uint4*)wbt;
        uint4* d = (uint4*)sB;
        for (int i = tid; i < 1600; i += 256) d[i] = s[i];
    }
    __syncthreads();
    int wid = tid >> 6, lane = tid & 63;
    int mtile = blockIdx.x * 4 + wid;
    if (mtile >= MTILES) return;
    int m0 = mtile * 16;
    int c = lane & 15, kg = lane >> 4;
    f32x4 z = {0.f, 0.f, 0.f, 0.f};
    f32x4 acc0 = z, acc1 = z, acc2 = z, acc3 = z;
    const unsigned short* Arow = A + (size_t)(m0 + c) * 192 + kg * 8;
#pragma unroll
    for (int ks = 0; ks < 6; ++ks) {
        short8 af = *(const short8*)(Arow + ks * 32);
        const unsigned short* bb = sB + kg * 8 + ks * 32;
        short8 b0 = *(const short8*)(bb + (0 * 16 + c) * 200);
        short8 b1 = *(const short8*)(bb + (1 * 16 + c) * 200);
        short8 b2 = *(const short8*)(bb + (2 * 16 + c) * 200);
        short8 b3 = *(const short8*)(bb + (3 * 16 + c) * 200);
        acc0 = __builtin_amdgcn_mfma_f32_16x16x32_bf16(af, b0, acc0, 0, 0, 0);
        acc1 = __builtin_amdgcn_mfma_f32_16x16x32_bf16(af, b1, acc1, 0, 0, 0);
        acc2 = __builtin_amdgcn_mfma_f32_16x16x32_bf16(af, b2, acc2, 0, 0, 0);
        acc3 = __builtin_amdgcn_mfma_f32_16x16x32_bf16(af, b3, acc3, 0, 0, 0);
    }
    int mA = m0 + kg * 4;
    int nA = mA >> 1, nB = nA + 1;
    float fc0 = 0.f, fc1 = 0.f, fc2 = 0.f, fc3 = 0.f;
#pragma unroll
    for (int t = 0; t < 4; ++t) {
        f32x4 a = (t == 0) ? acc0 : (t == 1) ? acc1 : (t == 2) ? acc2 : acc3;
        int h = t * 16 + c;
        float bv = bias[h];
        float v0 = a[0] + bv, v1 = a[1] + bv, v2 = a[2] + bv, v3 = a[3] + bv;
        v0 = v0 > 0.f ? v0 : expm1f(v0);
        v1 = v1 > 0.f ? v1 : expm1f(v1);
        v2 = v2 > 0.f ? v2 : expm1f(v2);
        v3 = v3 > 0.f ? v3 : expm1f(v3);
        if (nA < Nn) hpout[(size_t)nA * 64 + h] = packbf(v0, v1);
        if (nB < Nn) hpout[(size_t)nB * 64 + h] = packbf(v2, v3);
        float fw = fc_w[h * Ll + l];
        fc0 = fmaf(v0, fw, fc0);
        fc1 = fmaf(v1, fw, fc1);
        fc2 = fmaf(v2, fw, fc2);
        fc3 = fmaf(v3, fw, fc3);
    }
#pragma unroll
    for (int d = 1; d < 16; d <<= 1) {
        fc0 += __shfl_xor(fc0, d, 64);
        fc1 += __shfl_xor(fc1, d, 64);
        fc2 += __shfl_xor(fc2, d, 64);
        fc3 += __shfl_xor(fc3, d, 64);
    }
    if (c == 0) {
        if (nA < Nn) { node[nA] += fc0; node[Nn + nA] += fc1; }
        if (nB < Nn) { node[nB] += fc2; node[Nn + nB] += fc3; }
    }
}

// ---- head ----------------------------------------------------------------

__global__ void lin1_kernel(const float* __restrict__ node, const float* __restrict__ w,
                            const float* __restrict__ fcb, float* __restrict__ h1acc) {
    int hfc = threadIdx.x;
    int n0 = blockIdx.x * 64;
    int nend = n0 + 64 < Nn ? n0 + 64 : Nn;
    float fb = fcb[0];
    float a0 = 0.f, a1 = 0.f;
    for (int n = n0; n < nend; ++n) {
        float wv = w[(size_t)n * HFCc + hfc];
        a0 += (node[n] + fb) * wv;
        a1 += (node[Nn + n] + fb) * wv;
    }
    atomicAdd(&h1acc[hfc], a0);
    atomicAdd(&h1acc[HFCc + hfc], a1);
}

__global__ void head_kernel(const float* __restrict__ h1acc, const float* __restrict__ l1b,
                            const float* __restrict__ w2, const float* __restrict__ b2,
                            float* __restrict__ out) {
    __shared__ float sh[HFCc];
    __shared__ float slog[NCc];
    __shared__ float s_lse;
    int tid = threadIdx.x;
    for (int b = 0; b < BSz; ++b) {
        float v = h1acc[b * HFCc + tid] + l1b[tid];
        v = v > 0.f ? v : expm1f(v);
        sh[tid] = v;
        __syncthreads();
        if (tid < NCc) {
            float s = b2[tid];
            for (int i = 0; i < HFCc; ++i) s += sh[i] * w2[i * NCc + tid];
            slog[tid] = s;
        }
        __syncthreads();
        if (tid == 0) {
            float m = slog[0];
            for (int c = 1; c < NCc; ++c) m = fmaxf(m, slog[c]);
            float se = 0.f;
            for (int c = 0; c < NCc; ++c) se += expf(slog[c] - m);
            s_lse = m + logf(se);
        }
        __syncthreads();
        if (tid < NCc) out[b * NCc + tid] = slog[tid] - s_lse;
        __syncthreads();
    }
}

extern "C" void kernel_launch(void* const* d_in, const int* in_sizes, int n_in,
                              void* d_out, int out_size, void* d_ws, size_t ws_size,
                              hipStream_t stream) {
    const float* x      = (const float*)d_in[0];
    const int*   ei     = (const int*)d_in[2];
    const float* pseudo = (const float*)d_in[3];
    const float* g1     = (const float*)d_in[4];
    const float* mu1    = (const float*)d_in[5];
    const float* sigma1 = (const float*)d_in[6];
    const float* root1  = (const float*)d_in[7];
    const float* b1     = (const float*)d_in[8];
    const float* gs     = (const float*)d_in[9];
    const float* mus    = (const float*)d_in[10];
    const float* sigmas = (const float*)d_in[11];
    const float* roots  = (const float*)d_in[12];
    const float* bs_p   = (const float*)d_in[13];
    const float* fc_w   = (const float*)d_in[14];
    const float* fc_b   = (const float*)d_in[15];
    const float* lin1_w = (const float*)d_in[16];
    const float* lin1_b = (const float*)d_in[17];
    const float* lin2_w = (const float*)d_in[18];
    const float* lin2_b = (const float*)d_in[19];
    float* out = (float*)d_out;

    const int* src = ei;
    const int* dst = ei + Ee;

    auto alignup = [](size_t v) { return (v + 255) & ~(size_t)255; };
    char* ws = (char*)d_ws;
    size_t off = 0;
    float*          node    = (float*)(ws + off);          off += alignup((size_t)BSz * Nn * 4);
    float*          h1acc   = (float*)(ws + off);          off += alignup((size_t)BSz * HFCc * 4);
    int*            offs    = (int*)(ws + off);            off += alignup((size_t)(Nn + 1) * 4);
    int*            cursor  = (int*)(ws + off);            off += alignup((size_t)Nn * 4);
    int*            loc     = (int*)(ws + off);            off += alignup((size_t)Nn * 4);
    int*            bsum    = (int*)(ws + off);            off += alignup((size_t)64 * 4);
    int*            csr_src = (int*)(ws + off);            off += alignup((size_t)Ee * 4);
    float2*         gauss   = (float2*)(ws + off);         off += alignup((size_t)Ll * Ee * 8);
    unsigned*       xi      = (unsigned*)(ws + off);       off += alignup((size_t)Nn * F_INc * 4);
    unsigned*       wbuf    = (unsigned*)(ws + off);       off += alignup((size_t)768 * 4);
    unsigned short* wbt     = (unsigned short*)(ws + off); off += alignup((size_t)3 * 64 * 200 * 2);
    unsigned short* Abuf    = (unsigned short*)(ws + off); off += alignup((size_t)(MROWS + 2) * 192 * 2);
    unsigned*       hpA     = (unsigned*)(ws + off);       off += alignup((size_t)Nn * 64 * 4);
    unsigned*       hpB     = (unsigned*)(ws + off);       off += alignup((size_t)Nn * 64 * 4);
    (void)ws_size; (void)in_sizes; (void)n_in; (void)out_size;

    zero_kernel<<<NBLK, 256, 0, stream>>>(cursor, h1acc);
    count_kernel<<<(Ee + 255) / 256, 256, 0, stream>>>(dst, cursor);
    scan_local<<<NBLK, 256, 0, stream>>>(cursor, loc, bsum);
    scan_tops<<<1, 64, 0, stream>>>(bsum);
    scan_fix<<<NBLK, 256, 0, stream>>>(loc, bsum, offs, cursor);
    pack_x<<<(Nn * F_INc + 255) / 256, 256, 0, stream>>>(x, xi);
    pack_weights<<<(3 * 64 * 200 + 255) / 256, 256, 0, stream>>>(g1, root1, gs, roots, wbuf, wbt);
    fill_kernel<<<(Ee + 255) / 256, 256, 0, stream>>>(src, dst, pseudo, cursor, csr_src, gauss,
                                                      mu1, sigma1, mus, sigmas);

    layer0_fused<<<(Nn + 7) / 8, 512, 0, stream>>>(xi, offs, csr_src, gauss, wbuf, wbuf + 512,
                                                   b1, fc_w, hpA, node);
    unsigned* prev = hpA;
    unsigned* next = hpB;
    int ggrid = (Nn + 3) / 4;
    int mgrid = (MTILES + 3) / 4;
    for (int l = 1; l < Ll; ++l) {
        const float* bb = bs_p + (size_t)(l - 1) * Hh;
        gatherA<<<ggrid, 512, 0, stream>>>(prev, offs, csr_src, gauss + (size_t)l * Ee, Abuf);
        mfma_combine<<<mgrid, 256, 0, stream>>>(Abuf, wbt + (size_t)(l - 1) * 12800,
                                                bb, fc_w, l, next, node);
        unsigned* t = prev; prev = next; next = t;
    }

    lin1_kernel<<<(Nn + 63) / 64, 256, 0, stream>>>(node, lin1_w, fc_b, h1acc);
    head_kernel<<<1, HFCc, 0, stream>>>(h1acc, lin1_b, lin2_w, lin2_b, out);
}

// Round 16
// 173.796 us; speedup vs baseline: 1.0891x; 1.0891x over previous
//
#include <hip/hip_runtime.h>
#include <hip/hip_bf16.h>

#define BSz 2
#define Nn 15135
#define Ee 242160
#define F_INc 8
#define Hh 64
#define Ll 4
#define HFCc 256
#define NCc 10
#define EPSg 1e-15f
#define NBLK ((Nn + 255) / 256)   // 60 scan blocks
#define MROWS (2 * Nn)            // 30270 A-rows (row = 2n + b)
#define MTILES ((MROWS + 15) / 16)

typedef __attribute__((ext_vector_type(8))) short short8;
typedef __attribute__((ext_vector_type(4))) float f32x4;

__device__ __forceinline__ float uf(unsigned u) { return __uint_as_float(u); }
__device__ __forceinline__ unsigned short bs16(float f) {
    unsigned b = __float_as_uint(f);
    return (unsigned short)((b + 0x7FFFu + ((b >> 16) & 1u)) >> 16);
}
__device__ __forceinline__ unsigned packbf(float a, float b) {
    return (unsigned)bs16(a) | ((unsigned)bs16(b) << 16);
}

// ---- init ----------------------------------------------------------------

__global__ void zero_kernel(int* __restrict__ cursor, float* __restrict__ h1acc) {
    int i = blockIdx.x * 256 + threadIdx.x;
    if (i < Nn) cursor[i] = 0;
    if (i < BSz * HFCc) h1acc[i] = 0.f;
}

// x (2,N,8) f32 -> xi[n*8+f] = packed bf16 {b0,b1}
__global__ void pack_x(const float* __restrict__ x, unsigned* __restrict__ xi) {
    int i = blockIdx.x * 256 + threadIdx.x;
    if (i < Nn * F_INc) xi[i] = packbf(x[i], x[(size_t)Nn * F_INc + i]);
}

// weights: wbuf u32[768] for layer0 (as R13); wbt ushort[3][64][200] = B^T
__global__ void pack_weights(const float* __restrict__ g1, const float* __restrict__ root1,
                             const float* __restrict__ gs, const float* __restrict__ roots,
                             unsigned* __restrict__ wbuf, unsigned short* __restrict__ wbt) {
    int i = blockIdx.x * 256 + threadIdx.x;
    if (i < 512) {
        int f = i >> 6, h = i & 63;
        wbuf[i] = packbf(g1[f * 128 + h], g1[f * 128 + 64 + h]);
    } else if (i < 768) {
        int j = i - 512; int f2 = j >> 6, h = j & 63;
        wbuf[i] = packbf(root1[(2 * f2) * 64 + h], root1[(2 * f2 + 1) * 64 + h]);
    }
    if (i < 3 * 64 * 200) {
        int l = i / 12800, r = i % 12800, c = r / 200, k = r % 200;
        const float* G = gs + (size_t)l * 64 * 128;
        const float* R = roots + (size_t)l * 64 * 64;
        float v = 0.f;
        if (k < 64)       v = G[k * 128 + c];
        else if (k < 128) v = G[(k - 64) * 128 + 64 + c];
        else if (k < 192) v = R[(k - 128) * 64 + c];
        wbt[i] = bs16(v);
    }
}

// ---- CSR build ----------------------------------------------------------

__global__ void count_kernel(const int* __restrict__ dst, int* __restrict__ cnt) {
    int e = blockIdx.x * blockDim.x + threadIdx.x;
    if (e < Ee) atomicAdd(&cnt[dst[e]], 1);
}

__global__ void scan_local(const int* __restrict__ cnt, int* __restrict__ loc,
                           int* __restrict__ bsum) {
    int tid = threadIdx.x, lane = tid & 63, w = tid >> 6;
    int i = blockIdx.x * 256 + tid;
    __shared__ int ws[4];
    int v = (i < Nn) ? cnt[i] : 0;
    int incl = v;
#pragma unroll
    for (int d = 1; d < 64; d <<= 1) {
        int t = __shfl_up(incl, d, 64);
        if (lane >= d) incl += t;
    }
    if (lane == 63) ws[w] = incl;
    __syncthreads();
    int pre = 0;
    for (int ww = 0; ww < w; ++ww) pre += ws[ww];
    if (i < Nn) loc[i] = pre + incl - v;
    if (tid == 255) bsum[blockIdx.x] = pre + incl;
}

__global__ void scan_tops(int* __restrict__ bsum) {
    int lane = threadIdx.x;
    int v = (lane < NBLK) ? bsum[lane] : 0;
    int incl = v;
#pragma unroll
    for (int d = 1; d < 64; d <<= 1) {
        int t = __shfl_up(incl, d, 64);
        if (lane >= d) incl += t;
    }
    if (lane < NBLK) bsum[lane] = incl - v;
}

__global__ void scan_fix(const int* __restrict__ loc, const int* __restrict__ bsum,
                         int* __restrict__ offs, int* __restrict__ cursor) {
    int i = blockIdx.x * 256 + threadIdx.x;
    if (i < Nn) {
        int o = loc[i] + bsum[blockIdx.x];
        offs[i] = o;
        cursor[i] = o;
    }
    if (i == 0) offs[Nn] = Ee;
}

// fill: ONLY csr_eid (4 B scattered write per edge)
__global__ void fill_kernel(const int* __restrict__ dst, int* __restrict__ cursor,
                            int* __restrict__ csr_eid) {
    int e = blockIdx.x * blockDim.x + threadIdx.x;
    if (e >= Ee) return;
    int p = atomicAdd(&cursor[dst[e]], 1);
    csr_eid[p] = e;
}

// gauss_all: coalesced pass over CSR slots; scattered READS of src/pseudo,
// coalesced writes of csr_src + gauss for all 4 layers.
__global__ void gauss_all(const int* __restrict__ csr_eid, const int* __restrict__ src,
                          const float* __restrict__ pseudo, int* __restrict__ csr_src,
                          float2* __restrict__ gauss,
                          const float* __restrict__ mu1, const float* __restrict__ sigma1,
                          const float* __restrict__ mus, const float* __restrict__ sigmas) {
    int p = blockIdx.x * blockDim.x + threadIdx.x;
    if (p >= Ee) return;
    int e = csr_eid[p];
    csr_src[p] = src[e];
    float2 ps = ((const float2*)pseudo)[e];
#pragma unroll
    for (int l = 0; l < Ll; ++l) {
        const float* mu = (l == 0) ? mu1 : mus + (l - 1) * 4;
        const float* sg = (l == 0) ? sigma1 : sigmas + (l - 1) * 4;
        float d00 = ps.x - mu[0], d01 = ps.y - mu[1];
        float d10 = ps.x - mu[2], d11 = ps.y - mu[3];
        float i00 = 1.f / (EPSg + sg[0] * sg[0]);
        float i01 = 1.f / (EPSg + sg[1] * sg[1]);
        float i10 = 1.f / (EPSg + sg[2] * sg[2]);
        float i11 = 1.f / (EPSg + sg[3] * sg[3]);
        float g0 = expf(-0.5f * (d00 * d00 * i00 + d01 * d01 * i01));
        float g1 = expf(-0.5f * (d10 * d10 * i10 + d11 * d11 * i11));
        gauss[(size_t)l * Ee + p] = make_float2(g0, g1);
    }
}

// ---- layer 0 fused (unchanged) -------------------------------------------
__global__ __launch_bounds__(512, 4)
void layer0_fused(const unsigned* __restrict__ xi, const int* __restrict__ offs,
                  const int* __restrict__ csr_src, const float2* __restrict__ gauss,
                  const unsigned* __restrict__ wG, const unsigned* __restrict__ wR,
                  const float* __restrict__ bias, const float* __restrict__ fc_w,
                  unsigned* __restrict__ hpout, float* __restrict__ node) {
    int tid = threadIdx.x;
    int lane = tid & 63;
    int r = tid >> 6;
    int n0 = blockIdx.x * 8;
    int n = n0 + r;
    __shared__ unsigned sG[F_INc * 64];
    __shared__ unsigned sR[4 * 64];
    __shared__ unsigned s_agg[8][2 * F_INc];
    __shared__ unsigned s_x[8][F_INc];
    if (tid < F_INc * 64) sG[tid] = wG[tid];
    if (tid < 256) sR[tid] = wR[tid];
    for (int idx = tid; idx < 8 * F_INc; idx += 512) {
        int rr = idx >> 3, ff = idx & 7;
        int gn = n0 + rr;
        s_x[rr][ff] = (gn < Nn) ? xi[(size_t)gn * F_INc + ff] : 0u;
    }
    if (n < Nn) {
        int esub = lane >> 3, f = lane & 7;
        int s0 = offs[n], s1 = offs[n + 1];
        float a00 = 0.f, a01 = 0.f, a10 = 0.f, a11 = 0.f;
        if (s1 > s0) {
            int last = s1 - 1;
            for (int p0 = s0; p0 <= last; p0 += 8) {
                int p = p0 + esub;
                int pc = p < last ? p : last;
                float2 g = gauss[pc];
                if (p > last) { g.x = 0.f; g.y = 0.f; }
                unsigned u = xi[csr_src[pc] * F_INc + f];
                float x0 = uf(u << 16), x1 = uf(u & 0xFFFF0000u);
                a00 += g.x * x0; a01 += g.x * x1;
                a10 += g.y * x0; a11 += g.y * x1;
            }
#pragma unroll
            for (int d = 8; d <= 32; d <<= 1) {
                a00 += __shfl_xor(a00, d, 64);
                a01 += __shfl_xor(a01, d, 64);
                a10 += __shfl_xor(a10, d, 64);
                a11 += __shfl_xor(a11, d, 64);
            }
        }
        if (lane < 8) {
            s_agg[r][f]         = packbf(a00, a01);
            s_agg[r][F_INc + f] = packbf(a10, a11);
        }
    }
    __syncthreads();
    if (n >= Nn) return;
    int h = lane;
    float dg = (float)(offs[n + 1] - offs[n]);
    if (dg < 1.f) dg = 1.f;
    float inv = 1.f / dg;
    float bv = bias[h];
    float aA0 = 0.f, aA1 = 0.f, aR0 = bv, aR1 = bv;
#pragma unroll
    for (int f = 0; f < F_INc; ++f) {
        unsigned g = sG[f * 64 + h];
        float gv0 = uf(g << 16), gv1 = uf(g & 0xFFFF0000u);
        unsigned u0 = s_agg[r][f], u1 = s_agg[r][F_INc + f];
        aA0 = fmaf(uf(u0 << 16), gv0, aA0);
        aA1 = fmaf(uf(u0 & 0xFFFF0000u), gv0, aA1);
        aA0 = fmaf(uf(u1 << 16), gv1, aA0);
        aA1 = fmaf(uf(u1 & 0xFFFF0000u), gv1, aA1);
    }
#pragma unroll
    for (int f2 = 0; f2 < 4; ++f2) {
        unsigned rp = sR[f2 * 64 + h];
        float rv0 = uf(rp << 16), rv1 = uf(rp & 0xFFFF0000u);
        unsigned p0 = s_x[r][2 * f2], p1 = s_x[r][2 * f2 + 1];
        aR0 = fmaf(uf(p0 << 16), rv0, aR0);
        aR1 = fmaf(uf(p0 & 0xFFFF0000u), rv0, aR1);
        aR0 = fmaf(uf(p1 << 16), rv1, aR0);
        aR1 = fmaf(uf(p1 & 0xFFFF0000u), rv1, aR1);
    }
    float val0 = fmaf(aA0, inv, aR0);
    float val1 = fmaf(aA1, inv, aR1);
    val0 = val0 > 0.f ? val0 : expm1f(val0);
    val1 = val1 > 0.f ? val1 : expm1f(val1);
    hpout[(size_t)n * 64 + h] = packbf(val0, val1);
    float fw = fc_w[h * Ll + 0];
    float r0 = val0 * fw, r1 = val1 * fw;
#pragma unroll
    for (int off = 32; off; off >>= 1) {
        r0 += __shfl_down(r0, off, 64);
        r1 += __shfl_down(r1, off, 64);
    }
    if (h == 0) { node[n] = r0; node[Nn + n] = r1; }
}

// ---- layers 1..3: gather -> A rows (R14 version: one wave per node) ------
__global__ void gatherA(const unsigned* __restrict__ hp, const int* __restrict__ offs,
                        const int* __restrict__ csr_src, const float2* __restrict__ gauss,
                        unsigned short* __restrict__ A) {
    int tid = threadIdx.x;
    int lane = tid & 63;
    int n = blockIdx.x * 4 + (tid >> 6);
    if (n >= Nn) return;
    int s0 = offs[n], s1 = offs[n + 1];
    float a00 = 0.f, a01 = 0.f, a10 = 0.f, a11 = 0.f;  // a[k][b]
    int p = s0;
    for (; p + 3 < s1; p += 4) {
        int sa = csr_src[p], sb = csr_src[p + 1], sc = csr_src[p + 2], sd = csr_src[p + 3];
        float2 ga = gauss[p], gb = gauss[p + 1], gc = gauss[p + 2], gd = gauss[p + 3];
        unsigned ua = hp[(size_t)sa * 64 + lane];
        unsigned ub = hp[(size_t)sb * 64 + lane];
        unsigned uc = hp[(size_t)sc * 64 + lane];
        unsigned ud = hp[(size_t)sd * 64 + lane];
        float xa0 = uf(ua << 16), xa1 = uf(ua & 0xFFFF0000u);
        float xb0 = uf(ub << 16), xb1 = uf(ub & 0xFFFF0000u);
        float xc0 = uf(uc << 16), xc1 = uf(uc & 0xFFFF0000u);
        float xd0 = uf(ud << 16), xd1 = uf(ud & 0xFFFF0000u);
        a00 += ga.x * xa0 + gb.x * xb0 + gc.x * xc0 + gd.x * xd0;
        a01 += ga.x * xa1 + gb.x * xb1 + gc.x * xc1 + gd.x * xd1;
        a10 += ga.y * xa0 + gb.y * xb0 + gc.y * xc0 + gd.y * xd0;
        a11 += ga.y * xa1 + gb.y * xb1 + gc.y * xc1 + gd.y * xd1;
    }
    for (; p < s1; ++p) {
        int sa = csr_src[p];
        float2 ga = gauss[p];
        unsigned ua = hp[(size_t)sa * 64 + lane];
        float xa0 = uf(ua << 16), xa1 = uf(ua & 0xFFFF0000u);
        a00 += ga.x * xa0; a01 += ga.x * xa1;
        a10 += ga.y * xa0; a11 += ga.y * xa1;
    }
    float dg = (float)(s1 - s0);
    if (dg < 1.f) dg = 1.f;
    float inv = 1.f / dg;
    unsigned short* r0 = A + (size_t)(2 * n) * 192;
    unsigned short* r1 = A + (size_t)(2 * n + 1) * 192;
    r0[lane]       = bs16(a00 * inv);
    r0[64 + lane]  = bs16(a10 * inv);
    r1[lane]       = bs16(a01 * inv);
    r1[64 + lane]  = bs16(a11 * inv);
    unsigned up = hp[(size_t)n * 64 + lane];
    r0[128 + lane] = (unsigned short)(up & 0xFFFFu);
    r1[128 + lane] = (unsigned short)(up >> 16);
}

// ---- MFMA combine (unchanged from R14) -----------------------------------
__global__ __launch_bounds__(256, 4)
void mfma_combine(const unsigned short* __restrict__ A, const unsigned short* __restrict__ wbt,
                  const float* __restrict__ bias, const float* __restrict__ fc_w, int l,
                  unsigned* __restrict__ hpout, float* __restrict__ node) {
    __shared__ unsigned short sB[64 * 200];
    int tid = threadIdx.x;
    {
        const uint4* s = (const uint4*)wbt;
        uint4* d = (uint4*)sB;
        for (int i = tid; i < 1600; i += 256) d[i] = s[i];
    }
    __syncthreads();
    int wid = tid >> 6, lane = tid & 63;
    int mtile = blockIdx.x * 4 + wid;
    if (mtile >= MTILES) return;
    int m0 = mtile * 16;
    int c = lane & 15, kg = lane >> 4;
    f32x4 z = {0.f, 0.f, 0.f, 0.f};
    f32x4 acc0 = z, acc1 = z, acc2 = z, acc3 = z;
    const unsigned short* Arow = A + (size_t)(m0 + c) * 192 + kg * 8;
#pragma unroll
    for (int ks = 0; ks < 6; ++ks) {
        short8 af = *(const short8*)(Arow + ks * 32);
        const unsigned short* bb = sB + kg * 8 + ks * 32;
        short8 b0 = *(const short8*)(bb + (0 * 16 + c) * 200);
        short8 b1 = *(const short8*)(bb + (1 * 16 + c) * 200);
        short8 b2 = *(const short8*)(bb + (2 * 16 + c) * 200);
        short8 b3 = *(const short8*)(bb + (3 * 16 + c) * 200);
        acc0 = __builtin_amdgcn_mfma_f32_16x16x32_bf16(af, b0, acc0, 0, 0, 0);
        acc1 = __builtin_amdgcn_mfma_f32_16x16x32_bf16(af, b1, acc1, 0, 0, 0);
        acc2 = __builtin_amdgcn_mfma_f32_16x16x32_bf16(af, b2, acc2, 0, 0, 0);
        acc3 = __builtin_amdgcn_mfma_f32_16x16x32_bf16(af, b3, acc3, 0, 0, 0);
    }
    int mA = m0 + kg * 4;
    int nA = mA >> 1, nB = nA + 1;
    float fc0 = 0.f, fc1 = 0.f, fc2 = 0.f, fc3 = 0.f;
#pragma unroll
    for (int t = 0; t < 4; ++t) {
        f32x4 a = (t == 0) ? acc0 : (t == 1) ? acc1 : (t == 2) ? acc2 : acc3;
        int h = t * 16 + c;
        float bv = bias[h];
        float v0 = a[0] + bv, v1 = a[1] + bv, v2 = a[2] + bv, v3 = a[3] + bv;
        v0 = v0 > 0.f ? v0 : expm1f(v0);
        v1 = v1 > 0.f ? v1 : expm1f(v1);
        v2 = v2 > 0.f ? v2 : expm1f(v2);
        v3 = v3 > 0.f ? v3 : expm1f(v3);
        if (nA < Nn) hpout[(size_t)nA * 64 + h] = packbf(v0, v1);
        if (nB < Nn) hpout[(size_t)nB * 64 + h] = packbf(v2, v3);
        float fw = fc_w[h * Ll + l];
        fc0 = fmaf(v0, fw, fc0);
        fc1 = fmaf(v1, fw, fc1);
        fc2 = fmaf(v2, fw, fc2);
        fc3 = fmaf(v3, fw, fc3);
    }
#pragma unroll
    for (int d = 1; d < 16; d <<= 1) {
        fc0 += __shfl_xor(fc0, d, 64);
        fc1 += __shfl_xor(fc1, d, 64);
        fc2 += __shfl_xor(fc2, d, 64);
        fc3 += __shfl_xor(fc3, d, 64);
    }
    if (c == 0) {
        if (nA < Nn) { node[nA] += fc0; node[Nn + nA] += fc1; }
        if (nB < Nn) { node[nB] += fc2; node[Nn + nB] += fc3; }
    }
}

// ---- head ----------------------------------------------------------------

__global__ void lin1_kernel(const float* __restrict__ node, const float* __restrict__ w,
                            const float* __restrict__ fcb, float* __restrict__ h1acc) {
    int hfc = threadIdx.x;
    int n0 = blockIdx.x * 64;
    int nend = n0 + 64 < Nn ? n0 + 64 : Nn;
    float fb = fcb[0];
    float a0 = 0.f, a1 = 0.f;
    for (int n = n0; n < nend; ++n) {
        float wv = w[(size_t)n * HFCc + hfc];
        a0 += (node[n] + fb) * wv;
        a1 += (node[Nn + n] + fb) * wv;
    }
    atomicAdd(&h1acc[hfc], a0);
    atomicAdd(&h1acc[HFCc + hfc], a1);
}

__global__ void head_kernel(const float* __restrict__ h1acc, const float* __restrict__ l1b,
                            const float* __restrict__ w2, const float* __restrict__ b2,
                            float* __restrict__ out) {
    __shared__ float sh[HFCc];
    __shared__ float slog[NCc];
    __shared__ float s_lse;
    int tid = threadIdx.x;
    for (int b = 0; b < BSz; ++b) {
        float v = h1acc[b * HFCc + tid] + l1b[tid];
        v = v > 0.f ? v : expm1f(v);
        sh[tid] = v;
        __syncthreads();
        if (tid < NCc) {
            float s = b2[tid];
            for (int i = 0; i < HFCc; ++i) s += sh[i] * w2[i * NCc + tid];
            slog[tid] = s;
        }
        __syncthreads();
        if (tid == 0) {
            float m = slog[0];
            for (int c = 1; c < NCc; ++c) m = fmaxf(m, slog[c]);
            float se = 0.f;
            for (int c = 0; c < NCc; ++c) se += expf(slog[c] - m);
            s_lse = m + logf(se);
        }
        __syncthreads();
        if (tid < NCc) out[b * NCc + tid] = slog[tid] - s_lse;
        __syncthreads();
    }
}

extern "C" void kernel_launch(void* const* d_in, const int* in_sizes, int n_in,
                              void* d_out, int out_size, void* d_ws, size_t ws_size,
                              hipStream_t stream) {
    const float* x      = (const float*)d_in[0];
    const int*   ei     = (const int*)d_in[2];
    const float* pseudo = (const float*)d_in[3];
    const float* g1     = (const float*)d_in[4];
    const float* mu1    = (const float*)d_in[5];
    const float* sigma1 = (const float*)d_in[6];
    const float* root1  = (const float*)d_in[7];
    const float* b1     = (const float*)d_in[8];
    const float* gs     = (const float*)d_in[9];
    const float* mus    = (const float*)d_in[10];
    const float* sigmas = (const float*)d_in[11];
    const float* roots  = (const float*)d_in[12];
    const float* bs_p   = (const float*)d_in[13];
    const float* fc_w   = (const float*)d_in[14];
    const float* fc_b   = (const float*)d_in[15];
    const float* lin1_w = (const float*)d_in[16];
    const float* lin1_b = (const float*)d_in[17];
    const float* lin2_w = (const float*)d_in[18];
    const float* lin2_b = (const float*)d_in[19];
    float* out = (float*)d_out;

    const int* src = ei;
    const int* dst = ei + Ee;

    auto alignup = [](size_t v) { return (v + 255) & ~(size_t)255; };
    char* ws = (char*)d_ws;
    size_t off = 0;
    float*          node    = (float*)(ws + off);          off += alignup((size_t)BSz * Nn * 4);
    float*          h1acc   = (float*)(ws + off);          off += alignup((size_t)BSz * HFCc * 4);
    int*            offs    = (int*)(ws + off);            off += alignup((size_t)(Nn + 1) * 4);
    int*            cursor  = (int*)(ws + off);            off += alignup((size_t)Nn * 4);
    int*            loc     = (int*)(ws + off);            off += alignup((size_t)Nn * 4);
    int*            bsum    = (int*)(ws + off);            off += alignup((size_t)64 * 4);
    int*            csr_eid = (int*)(ws + off);            off += alignup((size_t)Ee * 4);
    int*            csr_src = (int*)(ws + off);            off += alignup((size_t)Ee * 4);
    float2*         gauss   = (float2*)(ws + off);         off += alignup((size_t)Ll * Ee * 8);
    unsigned*       xi      = (unsigned*)(ws + off);       off += alignup((size_t)Nn * F_INc * 4);
    unsigned*       wbuf    = (unsigned*)(ws + off);       off += alignup((size_t)768 * 4);
    unsigned short* wbt     = (unsigned short*)(ws + off); off += alignup((size_t)3 * 64 * 200 * 2);
    unsigned short* Abuf    = (unsigned short*)(ws + off); off += alignup((size_t)(MROWS + 2) * 192 * 2);
    unsigned*       hpA     = (unsigned*)(ws + off);       off += alignup((size_t)Nn * 64 * 4);
    unsigned*       hpB     = (unsigned*)(ws + off);       off += alignup((size_t)Nn * 64 * 4);
    (void)ws_size; (void)in_sizes; (void)n_in; (void)out_size;

    zero_kernel<<<NBLK, 256, 0, stream>>>(cursor, h1acc);
    count_kernel<<<(Ee + 255) / 256, 256, 0, stream>>>(dst, cursor);
    scan_local<<<NBLK, 256, 0, stream>>>(cursor, loc, bsum);
    scan_tops<<<1, 64, 0, stream>>>(bsum);
    scan_fix<<<NBLK, 256, 0, stream>>>(loc, bsum, offs, cursor);
    pack_x<<<(Nn * F_INc + 255) / 256, 256, 0, stream>>>(x, xi);
    pack_weights<<<(3 * 64 * 200 + 255) / 256, 256, 0, stream>>>(g1, root1, gs, roots, wbuf, wbt);
    fill_kernel<<<(Ee + 255) / 256, 256, 0, stream>>>(dst, cursor, csr_eid);
    gauss_all<<<(Ee + 255) / 256, 256, 0, stream>>>(csr_eid, src, pseudo, csr_src, gauss,
                                                    mu1, sigma1, mus, sigmas);

    layer0_fused<<<(Nn + 7) / 8, 512, 0, stream>>>(xi, offs, csr_src, gauss, wbuf, wbuf + 512,
                                                   b1, fc_w, hpA, node);
    unsigned* prev = hpA;
    unsigned* next = hpB;
    int ggrid = (Nn + 3) / 4;
    int mgrid = (MTILES + 3) / 4;
    for (int l = 1; l < Ll; ++l) {
        const float* bb = bs_p + (size_t)(l - 1) * Hh;
        gatherA<<<ggrid, 256, 0, stream>>>(prev, offs, csr_src, gauss + (size_t)l * Ee, Abuf);
        mfma_combine<<<mgrid, 256, 0, stream>>>(Abuf, wbt + (size_t)(l - 1) * 12800,
                                                bb, fc_w, l, next, node);
        unsigned* t = prev; prev = next; next = t;
    }

    lin1_kernel<<<(Nn + 63) / 64, 256, 0, stream>>>(node, lin1_w, fc_b, h1acc);
    head_kernel<<<1, HFCc, 0, stream>>>(h1acc, lin1_b, lin2_w, lin2_b, out);
}

// Round 17
// 169.832 us; speedup vs baseline: 1.1146x; 1.0233x over previous
//
#include <hip/hip_runtime.h>
#include <hip/hip_bf16.h>

#define BSz 2
#define Nn 15135
#define Ee 242160
#define F_INc 8
#define Hh 64
#define Ll 4
#define HFCc 256
#define NCc 10
#define EPSg 1e-15f
#define NBLK ((Nn + 255) / 256)   // 60 scan blocks
#define MROWS (2 * Nn)            // 30270 A-rows (row = 2n + b)
#define MTILES ((MROWS + 15) / 16)

typedef __attribute__((ext_vector_type(8))) short short8;
typedef __attribute__((ext_vector_type(4))) float f32x4;

__device__ __forceinline__ float uf(unsigned u) { return __uint_as_float(u); }
__device__ __forceinline__ unsigned short bs16(float f) {
    unsigned b = __float_as_uint(f);
    return (unsigned short)((b + 0x7FFFu + ((b >> 16) & 1u)) >> 16);
}
__device__ __forceinline__ unsigned packbf(float a, float b) {
    return (unsigned)bs16(a) | ((unsigned)bs16(b) << 16);
}

// ---- init ----------------------------------------------------------------

__global__ void zero_kernel(int* __restrict__ cursor, float* __restrict__ h1acc) {
    int i = blockIdx.x * 256 + threadIdx.x;
    if (i < Nn) cursor[i] = 0;
    if (i < BSz * HFCc) h1acc[i] = 0.f;
}

// x (2,N,8) f32 -> xi[n*8+f] = packed bf16 {b0,b1}
__global__ void pack_x(const float* __restrict__ x, unsigned* __restrict__ xi) {
    int i = blockIdx.x * 256 + threadIdx.x;
    if (i < Nn * F_INc) xi[i] = packbf(x[i], x[(size_t)Nn * F_INc + i]);
}

// weights: wbuf u32[768] for layer0 (as R13); wbt ushort[3][64][200] = B^T
__global__ void pack_weights(const float* __restrict__ g1, const float* __restrict__ root1,
                             const float* __restrict__ gs, const float* __restrict__ roots,
                             unsigned* __restrict__ wbuf, unsigned short* __restrict__ wbt) {
    int i = blockIdx.x * 256 + threadIdx.x;
    if (i < 512) {
        int f = i >> 6, h = i & 63;
        wbuf[i] = packbf(g1[f * 128 + h], g1[f * 128 + 64 + h]);
    } else if (i < 768) {
        int j = i - 512; int f2 = j >> 6, h = j & 63;
        wbuf[i] = packbf(root1[(2 * f2) * 64 + h], root1[(2 * f2 + 1) * 64 + h]);
    }
    if (i < 3 * 64 * 200) {
        int l = i / 12800, r = i % 12800, c = r / 200, k = r % 200;
        const float* G = gs + (size_t)l * 64 * 128;
        const float* R = roots + (size_t)l * 64 * 64;
        float v = 0.f;
        if (k < 64)       v = G[k * 128 + c];
        else if (k < 128) v = G[(k - 64) * 128 + 64 + c];
        else if (k < 192) v = R[(k - 128) * 64 + c];
        wbt[i] = bs16(v);
    }
}

// ---- CSR build ----------------------------------------------------------

__global__ void count_kernel(const int* __restrict__ dst, int* __restrict__ cnt) {
    int e = blockIdx.x * blockDim.x + threadIdx.x;
    if (e < Ee) atomicAdd(&cnt[dst[e]], 1);
}

__global__ void scan_local(const int* __restrict__ cnt, int* __restrict__ loc,
                           int* __restrict__ bsum) {
    int tid = threadIdx.x, lane = tid & 63, w = tid >> 6;
    int i = blockIdx.x * 256 + tid;
    __shared__ int ws[4];
    int v = (i < Nn) ? cnt[i] : 0;
    int incl = v;
#pragma unroll
    for (int d = 1; d < 64; d <<= 1) {
        int t = __shfl_up(incl, d, 64);
        if (lane >= d) incl += t;
    }
    if (lane == 63) ws[w] = incl;
    __syncthreads();
    int pre = 0;
    for (int ww = 0; ww < w; ++ww) pre += ws[ww];
    if (i < Nn) loc[i] = pre + incl - v;
    if (tid == 255) bsum[blockIdx.x] = pre + incl;
}

__global__ void scan_tops(int* __restrict__ bsum) {
    int lane = threadIdx.x;
    int v = (lane < NBLK) ? bsum[lane] : 0;
    int incl = v;
#pragma unroll
    for (int d = 1; d < 64; d <<= 1) {
        int t = __shfl_up(incl, d, 64);
        if (lane >= d) incl += t;
    }
    if (lane < NBLK) bsum[lane] = incl - v;
}

__global__ void scan_fix(const int* __restrict__ loc, const int* __restrict__ bsum,
                         int* __restrict__ offs, int* __restrict__ cursor) {
    int i = blockIdx.x * 256 + threadIdx.x;
    if (i < Nn) {
        int o = loc[i] + bsum[blockIdx.x];
        offs[i] = o;
        cursor[i] = o;
    }
    if (i == 0) offs[Nn] = Ee;
}

// fill: ONLY csr_eid (4 B scattered write per edge)
__global__ void fill_kernel(const int* __restrict__ dst, int* __restrict__ cursor,
                            int* __restrict__ csr_eid) {
    int e = blockIdx.x * blockDim.x + threadIdx.x;
    if (e >= Ee) return;
    int p = atomicAdd(&cursor[dst[e]], 1);
    csr_eid[p] = e;
}

// gauss_all: coalesced pass over CSR slots
__global__ void gauss_all(const int* __restrict__ csr_eid, const int* __restrict__ src,
                          const float* __restrict__ pseudo, int* __restrict__ csr_src,
                          float2* __restrict__ gauss,
                          const float* __restrict__ mu1, const float* __restrict__ sigma1,
                          const float* __restrict__ mus, const float* __restrict__ sigmas) {
    int p = blockIdx.x * blockDim.x + threadIdx.x;
    if (p >= Ee) return;
    int e = csr_eid[p];
    csr_src[p] = src[e];
    float2 ps = ((const float2*)pseudo)[e];
#pragma unroll
    for (int l = 0; l < Ll; ++l) {
        const float* mu = (l == 0) ? mu1 : mus + (l - 1) * 4;
        const float* sg = (l == 0) ? sigma1 : sigmas + (l - 1) * 4;
        float d00 = ps.x - mu[0], d01 = ps.y - mu[1];
        float d10 = ps.x - mu[2], d11 = ps.y - mu[3];
        float i00 = 1.f / (EPSg + sg[0] * sg[0]);
        float i01 = 1.f / (EPSg + sg[1] * sg[1]);
        float i10 = 1.f / (EPSg + sg[2] * sg[2]);
        float i11 = 1.f / (EPSg + sg[3] * sg[3]);
        float g0 = expf(-0.5f * (d00 * d00 * i00 + d01 * d01 * i01));
        float g1 = expf(-0.5f * (d10 * d10 * i10 + d11 * d11 * i11));
        gauss[(size_t)l * Ee + p] = make_float2(g0, g1);
    }
}

// ---- layer 0 fused (unchanged) -------------------------------------------
__global__ __launch_bounds__(512, 4)
void layer0_fused(const unsigned* __restrict__ xi, const int* __restrict__ offs,
                  const int* __restrict__ csr_src, const float2* __restrict__ gauss,
                  const unsigned* __restrict__ wG, const unsigned* __restrict__ wR,
                  const float* __restrict__ bias, const float* __restrict__ fc_w,
                  unsigned* __restrict__ hpout, float* __restrict__ node) {
    int tid = threadIdx.x;
    int lane = tid & 63;
    int r = tid >> 6;
    int n0 = blockIdx.x * 8;
    int n = n0 + r;
    __shared__ unsigned sG[F_INc * 64];
    __shared__ unsigned sR[4 * 64];
    __shared__ unsigned s_agg[8][2 * F_INc];
    __shared__ unsigned s_x[8][F_INc];
    if (tid < F_INc * 64) sG[tid] = wG[tid];
    if (tid < 256) sR[tid] = wR[tid];
    for (int idx = tid; idx < 8 * F_INc; idx += 512) {
        int rr = idx >> 3, ff = idx & 7;
        int gn = n0 + rr;
        s_x[rr][ff] = (gn < Nn) ? xi[(size_t)gn * F_INc + ff] : 0u;
    }
    if (n < Nn) {
        int esub = lane >> 3, f = lane & 7;
        int s0 = offs[n], s1 = offs[n + 1];
        float a00 = 0.f, a01 = 0.f, a10 = 0.f, a11 = 0.f;
        if (s1 > s0) {
            int last = s1 - 1;
            for (int p0 = s0; p0 <= last; p0 += 8) {
                int p = p0 + esub;
                int pc = p < last ? p : last;
                float2 g = gauss[pc];
                if (p > last) { g.x = 0.f; g.y = 0.f; }
                unsigned u = xi[csr_src[pc] * F_INc + f];
                float x0 = uf(u << 16), x1 = uf(u & 0xFFFF0000u);
                a00 += g.x * x0; a01 += g.x * x1;
                a10 += g.y * x0; a11 += g.y * x1;
            }
#pragma unroll
            for (int d = 8; d <= 32; d <<= 1) {
                a00 += __shfl_xor(a00, d, 64);
                a01 += __shfl_xor(a01, d, 64);
                a10 += __shfl_xor(a10, d, 64);
                a11 += __shfl_xor(a11, d, 64);
            }
        }
        if (lane < 8) {
            s_agg[r][f]         = packbf(a00, a01);
            s_agg[r][F_INc + f] = packbf(a10, a11);
        }
    }
    __syncthreads();
    if (n >= Nn) return;
    int h = lane;
    float dg = (float)(offs[n + 1] - offs[n]);
    if (dg < 1.f) dg = 1.f;
    float inv = 1.f / dg;
    float bv = bias[h];
    float aA0 = 0.f, aA1 = 0.f, aR0 = bv, aR1 = bv;
#pragma unroll
    for (int f = 0; f < F_INc; ++f) {
        unsigned g = sG[f * 64 + h];
        float gv0 = uf(g << 16), gv1 = uf(g & 0xFFFF0000u);
        unsigned u0 = s_agg[r][f], u1 = s_agg[r][F_INc + f];
        aA0 = fmaf(uf(u0 << 16), gv0, aA0);
        aA1 = fmaf(uf(u0 & 0xFFFF0000u), gv0, aA1);
        aA0 = fmaf(uf(u1 << 16), gv1, aA0);
        aA1 = fmaf(uf(u1 & 0xFFFF0000u), gv1, aA1);
    }
#pragma unroll
    for (int f2 = 0; f2 < 4; ++f2) {
        unsigned rp = sR[f2 * 64 + h];
        float rv0 = uf(rp << 16), rv1 = uf(rp & 0xFFFF0000u);
        unsigned p0 = s_x[r][2 * f2], p1 = s_x[r][2 * f2 + 1];
        aR0 = fmaf(uf(p0 << 16), rv0, aR0);
        aR1 = fmaf(uf(p0 & 0xFFFF0000u), rv0, aR1);
        aR0 = fmaf(uf(p1 << 16), rv1, aR0);
        aR1 = fmaf(uf(p1 & 0xFFFF0000u), rv1, aR1);
    }
    float val0 = fmaf(aA0, inv, aR0);
    float val1 = fmaf(aA1, inv, aR1);
    val0 = val0 > 0.f ? val0 : expm1f(val0);
    val1 = val1 > 0.f ? val1 : expm1f(val1);
    hpout[(size_t)n * 64 + h] = packbf(val0, val1);
    float fw = fc_w[h * Ll + 0];
    float r0 = val0 * fw, r1 = val1 * fw;
#pragma unroll
    for (int off = 32; off; off >>= 1) {
        r0 += __shfl_down(r0, off, 64);
        r1 += __shfl_down(r1, off, 64);
    }
    if (h == 0) { node[n] = r0; node[Nn + n] = r1; }
}

// ---- layers 1..3: gather -> A rows; half-wave per edge, uint2 loads ------
// lane = (sub, c): sub=lane>>5 picks odd/even edges, c=lane&31 -> channels 2c,2c+1.
__global__ void gatherA(const unsigned* __restrict__ hp, const int* __restrict__ offs,
                        const int* __restrict__ csr_src, const float2* __restrict__ gauss,
                        unsigned short* __restrict__ A) {
    int tid = threadIdx.x;
    int lane = tid & 63;
    int n = blockIdx.x * 4 + (tid >> 6);
    if (n >= Nn) return;
    int c = lane & 31;
    int sub = lane >> 5;
    int s0 = offs[n], s1 = offs[n + 1];
    // acc[k][b][chpair-half]: x = channel 2c, y = channel 2c+1
    float aK0B0x = 0.f, aK0B0y = 0.f, aK0B1x = 0.f, aK0B1y = 0.f;
    float aK1B0x = 0.f, aK1B0y = 0.f, aK1B1x = 0.f, aK1B1y = 0.f;
    int p = s0 + sub;
    for (; p + 6 < s1; p += 8) {
        int sa = csr_src[p], sb = csr_src[p + 2], sc = csr_src[p + 4], sd = csr_src[p + 6];
        float2 ga = gauss[p], gb = gauss[p + 2], gc = gauss[p + 4], gd = gauss[p + 6];
        uint2 ua = *(const uint2*)&hp[(size_t)sa * 64 + 2 * c];
        uint2 ub = *(const uint2*)&hp[(size_t)sb * 64 + 2 * c];
        uint2 uc = *(const uint2*)&hp[(size_t)sc * 64 + 2 * c];
        uint2 ud = *(const uint2*)&hp[(size_t)sd * 64 + 2 * c];
        {
            float xb0 = uf(ua.x << 16), xb1 = uf(ua.x & 0xFFFF0000u);
            float yb0 = uf(ua.y << 16), yb1 = uf(ua.y & 0xFFFF0000u);
            aK0B0x += ga.x * xb0; aK0B1x += ga.x * xb1;
            aK1B0x += ga.y * xb0; aK1B1x += ga.y * xb1;
            aK0B0y += ga.x * yb0; aK0B1y += ga.x * yb1;
            aK1B0y += ga.y * yb0; aK1B1y += ga.y * yb1;
        }
        {
            float xb0 = uf(ub.x << 16), xb1 = uf(ub.x & 0xFFFF0000u);
            float yb0 = uf(ub.y << 16), yb1 = uf(ub.y & 0xFFFF0000u);
            aK0B0x += gb.x * xb0; aK0B1x += gb.x * xb1;
            aK1B0x += gb.y * xb0; aK1B1x += gb.y * xb1;
            aK0B0y += gb.x * yb0; aK0B1y += gb.x * yb1;
            aK1B0y += gb.y * yb0; aK1B1y += gb.y * yb1;
        }
        {
            float xb0 = uf(uc.x << 16), xb1 = uf(uc.x & 0xFFFF0000u);
            float yb0 = uf(uc.y << 16), yb1 = uf(uc.y & 0xFFFF0000u);
            aK0B0x += gc.x * xb0; aK0B1x += gc.x * xb1;
            aK1B0x += gc.y * xb0; aK1B1x += gc.y * xb1;
            aK0B0y += gc.x * yb0; aK0B1y += gc.x * yb1;
            aK1B0y += gc.y * yb0; aK1B1y += gc.y * yb1;
        }
        {
            float xb0 = uf(ud.x << 16), xb1 = uf(ud.x & 0xFFFF0000u);
            float yb0 = uf(ud.y << 16), yb1 = uf(ud.y & 0xFFFF0000u);
            aK0B0x += gd.x * xb0; aK0B1x += gd.x * xb1;
            aK1B0x += gd.y * xb0; aK1B1x += gd.y * xb1;
            aK0B0y += gd.x * yb0; aK0B1y += gd.x * yb1;
            aK1B0y += gd.y * yb0; aK1B1y += gd.y * yb1;
        }
    }
    for (; p < s1; p += 2) {
        int sa = csr_src[p];
        float2 ga = gauss[p];
        uint2 ua = *(const uint2*)&hp[(size_t)sa * 64 + 2 * c];
        float xb0 = uf(ua.x << 16), xb1 = uf(ua.x & 0xFFFF0000u);
        float yb0 = uf(ua.y << 16), yb1 = uf(ua.y & 0xFFFF0000u);
        aK0B0x += ga.x * xb0; aK0B1x += ga.x * xb1;
        aK1B0x += ga.y * xb0; aK1B1x += ga.y * xb1;
        aK0B0y += ga.x * yb0; aK0B1y += ga.x * yb1;
        aK1B0y += ga.y * yb0; aK1B1y += ga.y * yb1;
    }
    // merge the two half-wave edge groups
    aK0B0x += __shfl_xor(aK0B0x, 32, 64);
    aK0B0y += __shfl_xor(aK0B0y, 32, 64);
    aK0B1x += __shfl_xor(aK0B1x, 32, 64);
    aK0B1y += __shfl_xor(aK0B1y, 32, 64);
    aK1B0x += __shfl_xor(aK1B0x, 32, 64);
    aK1B0y += __shfl_xor(aK1B0y, 32, 64);
    aK1B1x += __shfl_xor(aK1B1x, 32, 64);
    aK1B1y += __shfl_xor(aK1B1y, 32, 64);
    float dg = (float)(s1 - s0);
    if (dg < 1.f) dg = 1.f;
    float inv = 1.f / dg;
    unsigned short* r0 = A + (size_t)(2 * n) * 192;
    unsigned short* r1 = A + (size_t)(2 * n + 1) * 192;
    if (sub == 0) {
        unsigned* r0u = (unsigned*)r0;
        unsigned* r1u = (unsigned*)r1;
        r0u[c]      = packbf(aK0B0x * inv, aK0B0y * inv);
        r0u[32 + c] = packbf(aK1B0x * inv, aK1B0y * inv);
        r1u[c]      = packbf(aK0B1x * inv, aK0B1y * inv);
        r1u[32 + c] = packbf(aK1B1x * inv, aK1B1y * inv);
    }
    unsigned up = hp[(size_t)n * 64 + lane];
    r0[128 + lane] = (unsigned short)(up & 0xFFFFu);
    r1[128 + lane] = (unsigned short)(up >> 16);
}

// ---- MFMA combine (unchanged from R14) -----------------------------------
__global__ __launch_bounds__(256, 4)
void mfma_combine(const unsigned short* __restrict__ A, const unsigned short* __restrict__ wbt,
                  const float* __restrict__ bias, const float* __restrict__ fc_w, int l,
                  unsigned* __restrict__ hpout, float* __restrict__ node) {
    __shared__ unsigned short sB[64 * 200];
    int tid = threadIdx.x;
    {
        const uint4* s = (const uint4*)wbt;
        uint4* d = (uint4*)sB;
        for (int i = tid; i < 1600; i += 256) d[i] = s[i];
    }
    __syncthreads();
    int wid = tid >> 6, lane = tid & 63;
    int mtile = blockIdx.x * 4 + wid;
    if (mtile >= MTILES) return;
    int m0 = mtile * 16;
    int c = lane & 15, kg = lane >> 4;
    f32x4 z = {0.f, 0.f, 0.f, 0.f};
    f32x4 acc0 = z, acc1 = z, acc2 = z, acc3 = z;
    const unsigned short* Arow = A + (size_t)(m0 + c) * 192 + kg * 8;
#pragma unroll
    for (int ks = 0; ks < 6; ++ks) {
        short8 af = *(const short8*)(Arow + ks * 32);
        const unsigned short* bb = sB + kg * 8 + ks * 32;
        short8 b0 = *(const short8*)(bb + (0 * 16 + c) * 200);
        short8 b1 = *(const short8*)(bb + (1 * 16 + c) * 200);
        short8 b2 = *(const short8*)(bb + (2 * 16 + c) * 200);
        short8 b3 = *(const short8*)(bb + (3 * 16 + c) * 200);
        acc0 = __builtin_amdgcn_mfma_f32_16x16x32_bf16(af, b0, acc0, 0, 0, 0);
        acc1 = __builtin_amdgcn_mfma_f32_16x16x32_bf16(af, b1, acc1, 0, 0, 0);
        acc2 = __builtin_amdgcn_mfma_f32_16x16x32_bf16(af, b2, acc2, 0, 0, 0);
        acc3 = __builtin_amdgcn_mfma_f32_16x16x32_bf16(af, b3, acc3, 0, 0, 0);
    }
    int mA = m0 + kg * 4;
    int nA = mA >> 1, nB = nA + 1;
    float fc0 = 0.f, fc1 = 0.f, fc2 = 0.f, fc3 = 0.f;
#pragma unroll
    for (int t = 0; t < 4; ++t) {
        f32x4 a = (t == 0) ? acc0 : (t == 1) ? acc1 : (t == 2) ? acc2 : acc3;
        int h = t * 16 + c;
        float bv = bias[h];
        float v0 = a[0] + bv, v1 = a[1] + bv, v2 = a[2] + bv, v3 = a[3] + bv;
        v0 = v0 > 0.f ? v0 : expm1f(v0);
        v1 = v1 > 0.f ? v1 : expm1f(v1);
        v2 = v2 > 0.f ? v2 : expm1f(v2);
        v3 = v3 > 0.f ? v3 : expm1f(v3);
        if (nA < Nn) hpout[(size_t)nA * 64 + h] = packbf(v0, v1);
        if (nB < Nn) hpout[(size_t)nB * 64 + h] = packbf(v2, v3);
        float fw = fc_w[h * Ll + l];
        fc0 = fmaf(v0, fw, fc0);
        fc1 = fmaf(v1, fw, fc1);
        fc2 = fmaf(v2, fw, fc2);
        fc3 = fmaf(v3, fw, fc3);
    }
#pragma unroll
    for (int d = 1; d < 16; d <<= 1) {
        fc0 += __shfl_xor(fc0, d, 64);
        fc1 += __shfl_xor(fc1, d, 64);
        fc2 += __shfl_xor(fc2, d, 64);
        fc3 += __shfl_xor(fc3, d, 64);
    }
    if (c == 0) {
        if (nA < Nn) { node[nA] += fc0; node[Nn + nA] += fc1; }
        if (nB < Nn) { node[nB] += fc2; node[Nn + nB] += fc3; }
    }
}

// ---- head ----------------------------------------------------------------

__global__ void lin1_kernel(const float* __restrict__ node, const float* __restrict__ w,
                            const float* __restrict__ fcb, float* __restrict__ h1acc) {
    int hfc = threadIdx.x;
    int n0 = blockIdx.x * 64;
    int nend = n0 + 64 < Nn ? n0 + 64 : Nn;
    float fb = fcb[0];
    float a0 = 0.f, a1 = 0.f;
    for (int n = n0; n < nend; ++n) {
        float wv = w[(size_t)n * HFCc + hfc];
        a0 += (node[n] + fb) * wv;
        a1 += (node[Nn + n] + fb) * wv;
    }
    atomicAdd(&h1acc[hfc], a0);
    atomicAdd(&h1acc[HFCc + hfc], a1);
}

__global__ void head_kernel(const float* __restrict__ h1acc, const float* __restrict__ l1b,
                            const float* __restrict__ w2, const float* __restrict__ b2,
                            float* __restrict__ out) {
    __shared__ float sh[HFCc];
    __shared__ float slog[NCc];
    __shared__ float s_lse;
    int tid = threadIdx.x;
    for (int b = 0; b < BSz; ++b) {
        float v = h1acc[b * HFCc + tid] + l1b[tid];
        v = v > 0.f ? v : expm1f(v);
        sh[tid] = v;
        __syncthreads();
        if (tid < NCc) {
            float s = b2[tid];
            for (int i = 0; i < HFCc; ++i) s += sh[i] * w2[i * NCc + tid];
            slog[tid] = s;
        }
        __syncthreads();
        if (tid == 0) {
            float m = slog[0];
            for (int c = 1; c < NCc; ++c) m = fmaxf(m, slog[c]);
            float se = 0.f;
            for (int c = 0; c < NCc; ++c) se += expf(slog[c] - m);
            s_lse = m + logf(se);
        }
        __syncthreads();
        if (tid < NCc) out[b * NCc + tid] = slog[tid] - s_lse;
        __syncthreads();
    }
}

extern "C" void kernel_launch(void* const* d_in, const int* in_sizes, int n_in,
                              void* d_out, int out_size, void* d_ws, size_t ws_size,
                              hipStream_t stream) {
    const float* x      = (const float*)d_in[0];
    const int*   ei     = (const int*)d_in[2];
    const float* pseudo = (const float*)d_in[3];
    const float* g1     = (const float*)d_in[4];
    const float* mu1    = (const float*)d_in[5];
    const float* sigma1 = (const float*)d_in[6];
    const float* root1  = (const float*)d_in[7];
    const float* b1     = (const float*)d_in[8];
    const float* gs     = (const float*)d_in[9];
    const float* mus    = (const float*)d_in[10];
    const float* sigmas = (const float*)d_in[11];
    const float* roots  = (const float*)d_in[12];
    const float* bs_p   = (const float*)d_in[13];
    const float* fc_w   = (const float*)d_in[14];
    const float* fc_b   = (const float*)d_in[15];
    const float* lin1_w = (const float*)d_in[16];
    const float* lin1_b = (const float*)d_in[17];
    const float* lin2_w = (const float*)d_in[18];
    const float* lin2_b = (const float*)d_in[19];
    float* out = (float*)d_out;

    const int* src = ei;
    const int* dst = ei + Ee;

    auto alignup = [](size_t v) { return (v + 255) & ~(size_t)255; };
    char* ws = (char*)d_ws;
    size_t off = 0;
    float*          node    = (float*)(ws + off);          off += alignup((size_t)BSz * Nn * 4);
    float*          h1acc   = (float*)(ws + off);          off += alignup((size_t)BSz * HFCc * 4);
    int*            offs    = (int*)(ws + off);            off += alignup((size_t)(Nn + 1) * 4);
    int*            cursor  = (int*)(ws + off);            off += alignup((size_t)Nn * 4);
    int*            loc     = (int*)(ws + off);            off += alignup((size_t)Nn * 4);
    int*            bsum    = (int*)(ws + off);            off += alignup((size_t)64 * 4);
    int*            csr_eid = (int*)(ws + off);            off += alignup((size_t)Ee * 4);
    int*            csr_src = (int*)(ws + off);            off += alignup((size_t)Ee * 4);
    float2*         gauss   = (float2*)(ws + off);         off += alignup((size_t)Ll * Ee * 8);
    unsigned*       xi      = (unsigned*)(ws + off);       off += alignup((size_t)Nn * F_INc * 4);
    unsigned*       wbuf    = (unsigned*)(ws + off);       off += alignup((size_t)768 * 4);
    unsigned short* wbt     = (unsigned short*)(ws + off); off += alignup((size_t)3 * 64 * 200 * 2);
    unsigned short* Abuf    = (unsigned short*)(ws + off); off += alignup((size_t)(MROWS + 2) * 192 * 2);
    unsigned*       hpA     = (unsigned*)(ws + off);       off += alignup((size_t)Nn * 64 * 4);
    unsigned*       hpB     = (unsigned*)(ws + off);       off += alignup((size_t)Nn * 64 * 4);
    (void)ws_size; (void)in_sizes; (void)n_in; (void)out_size;

    zero_kernel<<<NBLK, 256, 0, stream>>>(cursor, h1acc);
    count_kernel<<<(Ee + 255) / 256, 256, 0, stream>>>(dst, cursor);
    scan_local<<<NBLK, 256, 0, stream>>>(cursor, loc, bsum);
    scan_tops<<<1, 64, 0, stream>>>(bsum);
    scan_fix<<<NBLK, 256, 0, stream>>>(loc, bsum, offs, cursor);
    pack_x<<<(Nn * F_INc + 255) / 256, 256, 0, stream>>>(x, xi);
    pack_weights<<<(3 * 64 * 200 + 255) / 256, 256, 0, stream>>>(g1, root1, gs, roots, wbuf, wbt);
    fill_kernel<<<(Ee + 255) / 256, 256, 0, stream>>>(dst, cursor, csr_eid);
    gauss_all<<<(Ee + 255) / 256, 256, 0, stream>>>(csr_eid, src, pseudo, csr_src, gauss,
                                                    mu1, sigma1, mus, sigmas);

    layer0_fused<<<(Nn + 7) / 8, 512, 0, stream>>>(xi, offs, csr_src, gauss, wbuf, wbuf + 512,
                                                   b1, fc_w, hpA, node);
    unsigned* prev = hpA;
    unsigned* next = hpB;
    int ggrid = (Nn + 3) / 4;
    int mgrid = (MTILES + 3) / 4;
    for (int l = 1; l < Ll; ++l) {
        const float* bb = bs_p + (size_t)(l - 1) * Hh;
        gatherA<<<ggrid, 256, 0, stream>>>(prev, offs, csr_src, gauss + (size_t)l * Ee, Abuf);
        mfma_combine<<<mgrid, 256, 0, stream>>>(Abuf, wbt + (size_t)(l - 1) * 12800,
                                                bb, fc_w, l, next, node);
        unsigned* t = prev; prev = next; next = t;
    }

    lin1_kernel<<<(Nn + 63) / 64, 256, 0, stream>>>(node, lin1_w, fc_b, h1acc);
    head_kernel<<<1, HFCc, 0, stream>>>(h1acc, lin1_b, lin2_w, lin2_b, out);
}